// Round 6
// baseline (690.998 us; speedup 1.0000x reference)
//
#include <hip/hip_runtime.h>
#include <math.h>

#define N_NODES 8192
#define NFEAT 512
#define NHID 64
#define NHEADS 8
#define NCLASS 40
#define NCHUNK 128
#define CHUNK 64
#define NB 4096

using bf16x8 = __attribute__((ext_vector_type(8))) short;
using f32x4 = __attribute__((ext_vector_type(4))) float;

// ---- helpers ----
__device__ __forceinline__ ushort f2b(float f) {  // fp32 -> bf16 RNE
  uint u = __builtin_bit_cast(uint, f);
  u += 0x7FFFu + ((u >> 16) & 1u);
  return (ushort)(u >> 16);
}
__device__ __forceinline__ float b2f(ushort h) {
  uint u = (uint)h << 16;
  return __builtin_bit_cast(float, u);
}
__device__ __forceinline__ uint encf(float f) {  // sortable-ascending uint
  uint u = __builtin_bit_cast(uint, f);
  return u ^ ((u >> 31) ? 0xFFFFFFFFu : 0x80000000u);
}
__device__ __forceinline__ float decf(uint u) {
  u ^= ((u >> 31) ? 0x80000000u : 0xFFFFFFFFu);
  return __builtin_bit_cast(float, u);
}
__device__ __forceinline__ float3 load_rng(const uint* mm, int head) {
  float h = decf(mm[head * 2]);        // max f2
  float l = decf(~mm[head * 2 + 1]);   // min f2 (stored as max of ~enc)
  float scale = (float)NB / fmaxf(h - l, 1e-30f);
  return make_float3(l, scale, h);
}
__device__ __forceinline__ int bucket_of(float v, float lo, float scale) {
  float u = fminf(fmaxf((v - lo) * scale, 0.f), (float)(NB - 1));
  return (int)u;
}

// ---------------- prep: split B' (=W transposed) into bf16 hi/lo planes + zero scratch ----
__global__ __launch_bounds__(256) void prep_k(const float* __restrict__ W_heads,
                                              ushort* __restrict__ bth,
                                              ushort* __restrict__ btl,
                                              float* __restrict__ zbase,
                                              int zcount) {
  int gid = blockIdx.x * 256 + threadIdx.x;
  int n = gid >> 9, c = gid & 511;
  int h = n >> 6, f = n & 63;
  float w = W_heads[((size_t)h * NFEAT + c) * NHID + f];
  ushort hh = f2b(w);
  bth[gid] = hh;
  btl[gid] = f2b(w - b2f(hh));
  if (gid < zcount) zbase[gid] = 0.f;  // zero mm/meanS/counters region
}

// ---------------- GEMM1: Wh(fp32) = x @ B' via split-bf16 MFMA (3 terms), 128x128 tiles ----
__global__ __launch_bounds__(256) void gemm1_k(const float* __restrict__ x,
                                               const ushort* __restrict__ bth,
                                               const ushort* __restrict__ btl,
                                               const float* __restrict__ a_heads,
                                               float* __restrict__ Wh,
                                               float* __restrict__ f1,
                                               float* __restrict__ f2,
                                               float* __restrict__ meanS,
                                               uint* __restrict__ mm1) {
  const int row0 = blockIdx.x * 128, col0 = blockIdx.y * 128;
  const int tid = threadIdx.x;
  const int wave = tid >> 6, lane = tid & 63;
  const int wr = wave >> 1, wc = wave & 1;
  __shared__ ushort Ah[128 * 40], Al[128 * 40], Bh[128 * 40], Bl[128 * 40];
  __shared__ float cs[2][64];
  __shared__ uint lmax[2], lmin[2];
  if (tid < 2) { lmax[tid] = 0u; lmin[tid] = 0u; }
  if (tid < 128) cs[tid >> 6][tid & 63] = 0.f;
  f32x4 acc[4][4] = {};
  const int sr = tid >> 1, sh = (tid & 1) * 16;
  const int fr = lane & 15, quad = lane >> 4;
  for (int k0 = 0; k0 < NFEAT; k0 += 32) {
    {
      const float* xs = x + (size_t)(row0 + sr) * NFEAT + k0 + sh;
      float av[16];
      *reinterpret_cast<float4*>(&av[0])  = *reinterpret_cast<const float4*>(xs);
      *reinterpret_cast<float4*>(&av[4])  = *reinterpret_cast<const float4*>(xs + 4);
      *reinterpret_cast<float4*>(&av[8])  = *reinterpret_cast<const float4*>(xs + 8);
      *reinterpret_cast<float4*>(&av[12]) = *reinterpret_cast<const float4*>(xs + 12);
      uint uh[8], ul[8];
#pragma unroll
      for (int q = 0; q < 8; ++q) {
        ushort h0 = f2b(av[2 * q]), h1 = f2b(av[2 * q + 1]);
        ushort l0 = f2b(av[2 * q] - b2f(h0)), l1 = f2b(av[2 * q + 1] - b2f(h1));
        uh[q] = (uint)h0 | ((uint)h1 << 16);
        ul[q] = (uint)l0 | ((uint)l1 << 16);
      }
      *reinterpret_cast<uint4*>(&Ah[sr * 40 + sh])     = make_uint4(uh[0], uh[1], uh[2], uh[3]);
      *reinterpret_cast<uint4*>(&Ah[sr * 40 + sh + 8]) = make_uint4(uh[4], uh[5], uh[6], uh[7]);
      *reinterpret_cast<uint4*>(&Al[sr * 40 + sh])     = make_uint4(ul[0], ul[1], ul[2], ul[3]);
      *reinterpret_cast<uint4*>(&Al[sr * 40 + sh + 8]) = make_uint4(ul[4], ul[5], ul[6], ul[7]);
      size_t boff = (size_t)(col0 + sr) * NFEAT + k0 + sh;
      *reinterpret_cast<uint4*>(&Bh[sr * 40 + sh])     = *reinterpret_cast<const uint4*>(bth + boff);
      *reinterpret_cast<uint4*>(&Bh[sr * 40 + sh + 8]) = *reinterpret_cast<const uint4*>(bth + boff + 8);
      *reinterpret_cast<uint4*>(&Bl[sr * 40 + sh])     = *reinterpret_cast<const uint4*>(btl + boff);
      *reinterpret_cast<uint4*>(&Bl[sr * 40 + sh + 8]) = *reinterpret_cast<const uint4*>(btl + boff + 8);
    }
    __syncthreads();
    bf16x8 afh[4], afl[4], bfh[4], bfl[4];
#pragma unroll
    for (int q = 0; q < 4; ++q) {
      afh[q] = *reinterpret_cast<const bf16x8*>(&Ah[(wr * 64 + q * 16 + fr) * 40 + quad * 8]);
      afl[q] = *reinterpret_cast<const bf16x8*>(&Al[(wr * 64 + q * 16 + fr) * 40 + quad * 8]);
      bfh[q] = *reinterpret_cast<const bf16x8*>(&Bh[(wc * 64 + q * 16 + fr) * 40 + quad * 8]);
      bfl[q] = *reinterpret_cast<const bf16x8*>(&Bl[(wc * 64 + q * 16 + fr) * 40 + quad * 8]);
    }
#pragma unroll
    for (int qr = 0; qr < 4; ++qr)
#pragma unroll
      for (int qc = 0; qc < 4; ++qc) {
        acc[qr][qc] = __builtin_amdgcn_mfma_f32_16x16x32_bf16(afl[qr], bfh[qc], acc[qr][qc], 0, 0, 0);
        acc[qr][qc] = __builtin_amdgcn_mfma_f32_16x16x32_bf16(afh[qr], bfl[qc], acc[qr][qc], 0, 0, 0);
        acc[qr][qc] = __builtin_amdgcn_mfma_f32_16x16x32_bf16(afh[qr], bfh[qc], acc[qr][qc], 0, 0, 0);
      }
    __syncthreads();
  }
  const int head = blockIdx.y * 2 + wc;
#pragma unroll
  for (int qr = 0; qr < 4; ++qr)
#pragma unroll
    for (int qc = 0; qc < 4; ++qc)
#pragma unroll
      for (int i = 0; i < 4; ++i) {
        int row = row0 + wr * 64 + qr * 16 + quad * 4 + i;
        int col = col0 + wc * 64 + qc * 16 + fr;
        Wh[(size_t)row * NFEAT + col] = acc[qr][qc][i];
      }
  const float* ah = a_heads + head * 2 * NHID;
  float a1v[4], a2v[4];
#pragma unroll
  for (int qc = 0; qc < 4; ++qc) { a1v[qc] = ah[qc * 16 + fr]; a2v[qc] = ah[NHID + qc * 16 + fr]; }
#pragma unroll
  for (int qr = 0; qr < 4; ++qr)
#pragma unroll
    for (int i = 0; i < 4; ++i) {
      float s1 = 0.f, s2 = 0.f;
#pragma unroll
      for (int qc = 0; qc < 4; ++qc) { s1 += acc[qr][qc][i] * a1v[qc]; s2 += acc[qr][qc][i] * a2v[qc]; }
#pragma unroll
      for (int m = 1; m < 16; m <<= 1) { s1 += __shfl_xor(s1, m, 64); s2 += __shfl_xor(s2, m, 64); }
      if (fr == 0) {
        int row = row0 + wr * 64 + qr * 16 + quad * 4 + i;
        f1[(head << 13) + row] = s1;
        f2[(head << 13) + row] = s2;
        atomicMax(&lmax[wc], encf(s2));
        atomicMax(&lmin[wc], ~encf(s2));
      }
    }
#pragma unroll
  for (int qc = 0; qc < 4; ++qc) {
    float v = 0.f;
#pragma unroll
    for (int qr = 0; qr < 4; ++qr)
#pragma unroll
      for (int i = 0; i < 4; ++i) v += acc[qr][qc][i];
    v += __shfl_xor(v, 16, 64);
    v += __shfl_xor(v, 32, 64);
    if (quad == 0) atomicAdd(&cs[wc][qc * 16 + fr], v);
  }
  __syncthreads();
  if (tid < 128) atomicAdd(&meanS[(blockIdx.y * 2 + (tid >> 6)) * NHID + (tid & 63)], cs[tid >> 6][tid & 63]);
  if (tid < 2) {
    atomicMax(&mm1[(blockIdx.y * 2 + tid) * 2], lmax[tid]);
    atomicMax(&mm1[(blockIdx.y * 2 + tid) * 2 + 1], lmin[tid]);
  }
}

// ---------------- GEMM2 fused: Wh2 = H @ W_out + f1b/f2b + colsums + minmax ----------------
__global__ __launch_bounds__(256) void gemm2_k(const float* __restrict__ H,
                                               const float* __restrict__ Wout,
                                               const float* __restrict__ a_out,
                                               float* __restrict__ Wh2,
                                               float* __restrict__ f1b,
                                               float* __restrict__ f2b,
                                               float* __restrict__ meanS2,
                                               uint* __restrict__ mm2) {
  const int row0 = blockIdx.x * 32;
  const int tid = threadIdx.x;
  __shared__ float As[32][33];
  __shared__ float Bs[32][40];
  __shared__ float cs[NCLASS];
  __shared__ uint lmax, lmin;
  if (tid < NCLASS) cs[tid] = 0.f;
  if (tid == 0) { lmax = 0u; lmin = 0u; }
  const int m = tid >> 3;
  const int n0 = (tid & 7) * 5;
  float acc[5] = {};
  for (int k0 = 0; k0 < NFEAT; k0 += 32) {
    {
      int kk = tid & 31, mq = tid >> 5;
#pragma unroll
      for (int r = 0; r < 4; ++r)
        As[kk][mq * 4 + r] = H[(size_t)(row0 + mq * 4 + r) * NFEAT + k0 + kk];
    }
    {
#pragma unroll
      for (int r = 0; r < 5; ++r) {
        int idx = tid + r * 256;
        if (idx < 1280) {
          int c = idx / 40, n = idx - c * 40;
          Bs[c][n] = Wout[(size_t)(k0 + c) * NCLASS + n];
        }
      }
    }
    __syncthreads();
#pragma unroll
    for (int kk = 0; kk < 32; ++kk) {
      float a = As[kk][m];
#pragma unroll
      for (int q = 0; q < 5; ++q) acc[q] += a * Bs[kk][n0 + q];
    }
    __syncthreads();
  }
#pragma unroll
  for (int q = 0; q < 5; ++q) Wh2[(size_t)(row0 + m) * NCLASS + n0 + q] = acc[q];
  float p1 = 0.f, p2 = 0.f;
#pragma unroll
  for (int q = 0; q < 5; ++q) {
    p1 += acc[q] * a_out[n0 + q];
    p2 += acc[q] * a_out[NCLASS + n0 + q];
  }
  p1 += __shfl_xor(p1, 1, 64); p1 += __shfl_xor(p1, 2, 64); p1 += __shfl_xor(p1, 4, 64);
  p2 += __shfl_xor(p2, 1, 64); p2 += __shfl_xor(p2, 2, 64); p2 += __shfl_xor(p2, 4, 64);
  if ((tid & 7) == 0) {
    f1b[row0 + m] = p1;
    f2b[row0 + m] = p2;
    atomicMax(&lmax, encf(p2));
    atomicMax(&lmin, ~encf(p2));
  }
#pragma unroll
  for (int q = 0; q < 5; ++q) atomicAdd(&cs[n0 + q], acc[q]);
  __syncthreads();
  if (tid < NCLASS) atomicAdd(&meanS2[tid], cs[tid]);
  if (tid == 0) { atomicMax(&mm2[0], lmax); atomicMax(&mm2[1], lmin); }
}

// ---------------- bucket: hist + prefix + scatter in one kernel, one block per head ----------
__global__ __launch_bounds__(1024) void bucket_k(const float* __restrict__ f2,
                                                 const uint* __restrict__ mm,
                                                 int* __restrict__ bs,
                                                 int* __restrict__ idxs,
                                                 float* __restrict__ f2s,
                                                 float* __restrict__ g) {
  __shared__ int sb[NB];
  const int head = blockIdx.x, tid = threadIdx.x;
  const int base = head * N_NODES;
  float3 rg = load_rng(mm, head);
#pragma unroll
  for (int r = 0; r < NB / 1024; ++r) sb[tid + r * 1024] = 0;
  __syncthreads();
  float v[8];
  int bk[8];
#pragma unroll
  for (int r = 0; r < 8; ++r) {
    v[r] = f2[base + tid + r * 1024];
    bk[r] = bucket_of(v[r], rg.x, rg.y);
    atomicAdd(&sb[bk[r]], 1);
  }
  __syncthreads();
  // inclusive prefix over NB
  for (int st = 1; st < NB; st <<= 1) {
    int t[NB / 1024];
#pragma unroll
    for (int r = 0; r < NB / 1024; ++r) { int i = tid + r * 1024; t[r] = (i >= st) ? sb[i - st] : 0; }
    __syncthreads();
#pragma unroll
    for (int r = 0; r < NB / 1024; ++r) sb[tid + r * 1024] += t[r];
    __syncthreads();
  }
  // write exclusive offsets to global (for query), then convert LDS to exclusive
  int ex[NB / 1024];
#pragma unroll
  for (int r = 0; r < NB / 1024; ++r) {
    int b = tid + r * 1024;
    ex[r] = b ? sb[b - 1] : 0;
    bs[head * (NB + 1) + b] = ex[r];
  }
  if (tid == 0) bs[head * (NB + 1) + NB] = sb[NB - 1];
  __syncthreads();
#pragma unroll
  for (int r = 0; r < NB / 1024; ++r) sb[tid + r * 1024] = ex[r];
  __syncthreads();
  // scatter via LDS atomic offsets
#pragma unroll
  for (int r = 0; r < 8; ++r) {
    int pos = atomicAdd(&sb[bk[r]], 1);
    int i = tid + r * 1024;
    idxs[base + pos] = i;
    f2s[base + pos] = v[r];
    g[base + pos] = expf(v[r] - rg.z);
  }
}

// ---------------- suffix scan: per-chunk local suffix + last-block-per-head chunk-total scan --
template <int F, int LD, int COLSTEP>
__global__ __launch_bounds__(256) void scanAB_k(const float* __restrict__ Wh,
                                                const float* __restrict__ g,
                                                const int* __restrict__ idxs,
                                                float* __restrict__ S,
                                                float* __restrict__ D,
                                                float* __restrict__ T_,
                                                float* __restrict__ Td,
                                                int* __restrict__ cntA) {
  constexpr int PAD = (F == 64) ? 66 : 42;
  constexpr int SZ1 = 64 * PAD + 4 * PAD + 64 + 4;
  constexpr int SZ2 = NCHUNK * F + NCHUNK;
  __shared__ float smem[SZ1 > SZ2 ? SZ1 : SZ2];
  __shared__ int isLast;
  float (*Sloc)[PAD] = (float(*)[PAD])smem;
  float* wtot  = smem + 64 * PAD;
  float* Dloc  = wtot + 4 * PAD;
  float* wtotD = Dloc + 64;
  const int head = blockIdx.y, chunk = blockIdx.x;
  const int tid = threadIdx.x, w = tid >> 6, lane = tid & 63;
  const int base = head << 13;
  const int kbase = base + chunk * CHUNK;
  int myj = 0; float myg = 0.f;
  if (lane < 16) {
    myj = idxs[kbase + w * 16 + lane];
    myg = g[kbase + w * 16 + lane];
  }
  float acc = 0.f, accD = 0.f;
#pragma unroll
  for (int kk = 15; kk >= 0; --kk) {
    int j = __shfl(myj, kk, 64);
    float gk = __shfl(myg, kk, 64);
    float wv = (lane < F) ? Wh[(size_t)j * LD + head * COLSTEP + lane] : 0.f;
    acc += gk * wv;
    accD += gk;
    if (lane < F) Sloc[w * 16 + kk][lane] = acc;
    if (lane == 0) Dloc[w * 16 + kk] = accD;
  }
  if (lane < F) wtot[w * PAD + lane] = acc;
  if (lane == 0) wtotD[w] = accD;
  __syncthreads();
  float off = 0.f, offD = 0.f;
#pragma unroll
  for (int w2 = 1; w2 < 4; ++w2) {
    if (w + w2 < 4) {
      off += (lane < F) ? wtot[(w + w2) * PAD + lane] : 0.f;
      offD += wtotD[w + w2];
    }
  }
#pragma unroll
  for (int kk = 0; kk < 16; ++kk) {
    int e = w * 16 + kk;
    if (lane < F) S[(size_t)(kbase + e) * F + lane] = Sloc[e][lane] + off;
    if (lane == 0) D[kbase + e] = Dloc[e] + offD;
  }
  if (w == 0) {
    if (lane < F) T_[(size_t)(head * NCHUNK + chunk) * F + lane] = wtot[lane] + off;
    if (lane == 0) Td[head * NCHUNK + chunk] = wtotD[0] + offD;
  }
  // ---- last block per head performs the chunk-total suffix scan (replaces scanB) ----
  __threadfence();
  if (tid == 0) isLast = (atomicAdd(&cntA[head], 1) == NCHUNK - 1);
  __syncthreads();
  if (!isLast) return;
  float* s  = smem;                 // NCHUNK * F
  float* td = smem + NCHUNK * F;    // NCHUNK
  for (int idx = tid; idx < NCHUNK * F; idx += 256) s[idx] = T_[(size_t)head * NCHUNK * F + idx];
  for (int c = tid; c < NCHUNK; c += 256) td[c] = Td[head * NCHUNK + c];
  __syncthreads();
  constexpr int PT = (NCHUNK * F + 255) / 256;
  for (int st = 1; st < NCHUNK; st <<= 1) {
    float tv[PT];
    int n = 0;
#pragma unroll
    for (int idx = tid; idx < NCHUNK * F; idx += 256, ++n) {
      int c = idx / F;
      tv[n] = (c + st < NCHUNK) ? s[idx + st * F] : 0.f;
    }
    float tdv = (tid < NCHUNK && tid + st < NCHUNK) ? td[tid + st] : 0.f;
    __syncthreads();
    n = 0;
#pragma unroll
    for (int idx = tid; idx < NCHUNK * F; idx += 256, ++n) s[idx] += tv[n];
    if (tid < NCHUNK) td[tid] += tdv;
    __syncthreads();
  }
  for (int idx = tid; idx < NCHUNK * F; idx += 256) T_[(size_t)head * NCHUNK * F + idx] = s[idx];
  for (int c = tid; c < NCHUNK; c += 256) Td[head * NCHUNK + c] = td[c];
}

// ---------------- layer-1 queries ----------------
__global__ __launch_bounds__(256) void query1_k(const float* __restrict__ f1,
                                                const float* __restrict__ f2s,
                                                const int* __restrict__ idxs,
                                                const float* __restrict__ Wh,
                                                const float* __restrict__ S,
                                                const float* __restrict__ D,
                                                const float* __restrict__ T_,
                                                const float* __restrict__ Td,
                                                const uint* __restrict__ mm,
                                                const int* __restrict__ bs,
                                                const float* __restrict__ meanS,
                                                float* __restrict__ H) {
  int w = blockIdx.x * 4 + (threadIdx.x >> 6);
  int lane = threadIdx.x & 63;
  int head = w & 7, i = w >> 3, base = head << 13;
  float t = f1[base + i];
  float3 rg = load_rng(mm, head);
  int B0 = bucket_of(-t, rg.x, rg.y);
  int p0 = bs[head * (NB + 1) + B0], p1 = bs[head * (NB + 1) + B0 + 1];
  float num = 0.f, den = 0.f;
  int cnt = N_NODES - p1;
  if (p1 < N_NODES) {
    int c = p1 >> 6;
    num = S[(size_t)(base + p1) * NHID + lane] +
          ((c + 1 < NCHUNK) ? T_[(size_t)(head * NCHUNK + c + 1) * NHID + lane] : 0.f);
    den = D[base + p1] + ((c + 1 < NCHUNK) ? Td[head * NCHUNK + c + 1] : 0.f);
  }
  for (int p = p0; p < p1; ++p) {
    float v = f2s[base + p];
    if (t + v > 0.f) {
      int j = idxs[base + p];
      float gk = expf(v - rg.z);
      num += gk * Wh[(size_t)j * NFEAT + head * NHID + lane];
      den += gk;
      ++cnt;
    }
  }
  float val = cnt ? num / den : meanS[head * NHID + lane] * (1.f / N_NODES);
  H[(size_t)i * NFEAT + head * NHID + lane] = (val > 0.f) ? val : expm1f(val);
}

// ---------------- layer-2 queries + elu + log_softmax ----------------
__global__ __launch_bounds__(256) void final_k(const float* __restrict__ f1b,
                                               const float* __restrict__ f2bs,
                                               const int* __restrict__ idx2,
                                               const float* __restrict__ Wh2,
                                               const float* __restrict__ S2,
                                               const float* __restrict__ D2,
                                               const float* __restrict__ T2,
                                               const float* __restrict__ Td2,
                                               const uint* __restrict__ mm2,
                                               const int* __restrict__ bs2,
                                               const float* __restrict__ meanS2,
                                               float* __restrict__ out) {
  int i = blockIdx.x * 4 + (threadIdx.x >> 6);
  int lane = threadIdx.x & 63;
  float t = f1b[i];
  float3 rg = load_rng(mm2, 0);
  int B0 = bucket_of(-t, rg.x, rg.y);
  int p0 = bs2[B0], p1 = bs2[B0 + 1];
  float num = 0.f, den = 0.f;
  int cnt = N_NODES - p1;
  if (p1 < N_NODES) {
    int c = p1 >> 6;
    num = (lane < NCLASS) ? (S2[(size_t)p1 * NCLASS + lane] +
                             ((c + 1 < NCHUNK) ? T2[(size_t)(c + 1) * NCLASS + lane] : 0.f))
                          : 0.f;
    den = D2[p1] + ((c + 1 < NCHUNK) ? Td2[c + 1] : 0.f);
  }
  for (int p = p0; p < p1; ++p) {
    float v = f2bs[p];
    if (t + v > 0.f) {
      int j = idx2[p];
      float gk = expf(v - rg.z);
      if (lane < NCLASS) num += gk * Wh2[(size_t)j * NCLASS + lane];
      den += gk;
      ++cnt;
    }
  }
  float o;
  if (lane < NCLASS) {
    float val = cnt ? num / den : meanS2[lane] * (1.f / N_NODES);
    o = (val > 0.f) ? val : expm1f(val);
  } else {
    o = -INFINITY;
  }
  float m = o;
#pragma unroll
  for (int msk = 32; msk; msk >>= 1) m = fmaxf(m, __shfl_xor(m, msk, 64));
  float e = (lane < NCLASS) ? expf(o - m) : 0.f;
#pragma unroll
  for (int msk = 32; msk; msk >>= 1) e += __shfl_xor(e, msk, 64);
  if (lane < NCLASS) out[(size_t)i * NCLASS + lane] = o - m - logf(e);
}

extern "C" void kernel_launch(void* const* d_in, const int* in_sizes, int n_in,
                              void* d_out, int out_size, void* d_ws, size_t ws_size,
                              hipStream_t stream) {
  const float* x       = (const float*)d_in[0];
  const float* W_heads = (const float*)d_in[2];
  const float* a_heads = (const float*)d_in[3];
  const float* W_out   = (const float*)d_in[4];
  const float* a_out   = (const float*)d_in[5];
  float* out = (float*)d_out;

  float* ws = (float*)d_ws;
  size_t o = 0;
  auto alloc = [&](size_t n) { float* p = ws + o; o += (n + 3) & ~(size_t)3; return p; };
  float*  S1     = alloc((size_t)NHEADS * N_NODES * NHID);   // 16 MB
  ushort* BTh    = (ushort*)alloc((size_t)NFEAT * NFEAT / 2);
  ushort* BTl    = (ushort*)alloc((size_t)NFEAT * NFEAT / 2);
  float*  Wh     = alloc((size_t)N_NODES * NFEAT);           // 16 MB fp32
  float*  H      = alloc((size_t)N_NODES * NFEAT);           // 16 MB
  float*  f1     = alloc(NHEADS * N_NODES);
  float*  f2     = alloc(NHEADS * N_NODES);
  float*  f2s    = alloc(NHEADS * N_NODES);
  int*    idxs   = (int*)alloc(NHEADS * N_NODES);
  float*  g1     = alloc(NHEADS * N_NODES);
  float*  D1     = alloc(NHEADS * N_NODES);
  float*  T1     = alloc(NHEADS * NCHUNK * NHID);
  float*  Td1    = alloc(NHEADS * NCHUNK);
  int*    bst1   = (int*)alloc(NHEADS * (NB + 1));
  float*  Wh2    = alloc((size_t)N_NODES * NCLASS);
  float*  S2     = alloc((size_t)N_NODES * NCLASS);
  float*  f1b    = alloc(N_NODES);
  float*  f2b    = alloc(N_NODES);
  float*  f2bs   = alloc(N_NODES);
  int*    idx2   = (int*)alloc(N_NODES);
  float*  g2     = alloc(N_NODES);
  float*  D2     = alloc(N_NODES);
  float*  T2     = alloc(NCHUNK * NCLASS);
  float*  Td2    = alloc(NCHUNK);
  int*    bst2   = (int*)alloc(NB + 1);
  // ---- contiguous zero region (zeroed by prep_k) ----
  float*  zbase  = ws + o;
  uint*   mm1    = (uint*)alloc(16);
  uint*   mm2    = (uint*)alloc(4);
  float*  meanS1 = alloc(NHEADS * NHID);
  float*  meanS2 = alloc(64);
  int*    cntA1  = (int*)alloc(NHEADS);
  int*    cntA2  = (int*)alloc(4);
  int zcount = (int)((ws + o) - zbase);

  // ---- layer 1 ----
  prep_k<<<1024, 256, 0, stream>>>(W_heads, BTh, BTl, zbase, zcount);
  gemm1_k<<<dim3(64, 4), 256, 0, stream>>>(x, BTh, BTl, a_heads, Wh, f1, f2, meanS1, mm1);
  bucket_k<<<NHEADS, 1024, 0, stream>>>(f2, mm1, bst1, idxs, f2s, g1);
  scanAB_k<NHID, NFEAT, NHID><<<dim3(NCHUNK, NHEADS), 256, 0, stream>>>(Wh, g1, idxs, S1, D1, T1, Td1, cntA1);
  query1_k<<<16384, 256, 0, stream>>>(f1, f2s, idxs, Wh, S1, D1, T1, Td1, mm1, bst1, meanS1, H);

  // ---- layer 2 ----
  gemm2_k<<<256, 256, 0, stream>>>(H, W_out, a_out, Wh2, f1b, f2b, meanS2, mm2);
  bucket_k<<<1, 1024, 0, stream>>>(f2b, mm2, bst2, idx2, f2bs, g2);
  scanAB_k<NCLASS, NCLASS, 0><<<dim3(NCHUNK, 1), 256, 0, stream>>>(Wh2, g2, idx2, S2, D2, T2, Td2, cntA2);
  final_k<<<2048, 256, 0, stream>>>(f1b, f2bs, idx2, Wh2, S2, D2, T2, Td2, mm2, bst2, meanS2, out);
}

// Round 7
// 536.654 us; speedup vs baseline: 1.2876x; 1.2876x over previous
//
#include <hip/hip_runtime.h>
#include <math.h>

#define N_NODES 8192
#define NFEAT 512
#define NHID 64
#define NHEADS 8
#define NCLASS 40
#define NCHUNK 128
#define CHUNK 64
#define NB 4096

using bf16x8 = __attribute__((ext_vector_type(8))) short;
using f32x4 = __attribute__((ext_vector_type(4))) float;

// ---- helpers ----
__device__ __forceinline__ ushort f2b(float f) {  // fp32 -> bf16 RNE
  uint u = __builtin_bit_cast(uint, f);
  u += 0x7FFFu + ((u >> 16) & 1u);
  return (ushort)(u >> 16);
}
__device__ __forceinline__ float b2f(ushort h) {
  uint u = (uint)h << 16;
  return __builtin_bit_cast(float, u);
}
__device__ __forceinline__ uint encf(float f) {  // sortable-ascending uint
  uint u = __builtin_bit_cast(uint, f);
  return u ^ ((u >> 31) ? 0xFFFFFFFFu : 0x80000000u);
}
__device__ __forceinline__ float decf(uint u) {
  u ^= ((u >> 31) ? 0x80000000u : 0xFFFFFFFFu);
  return __builtin_bit_cast(float, u);
}
__device__ __forceinline__ float3 load_rng(const uint* mm, int head) {
  float h = decf(mm[head * 2]);        // max f2
  float l = decf(~mm[head * 2 + 1]);   // min f2 (stored as max of ~enc)
  float scale = (float)NB / fmaxf(h - l, 1e-30f);
  return make_float3(l, scale, h);
}
__device__ __forceinline__ int bucket_of(float v, float lo, float scale) {
  float u = fminf(fmaxf((v - lo) * scale, 0.f), (float)(NB - 1));
  return (int)u;
}

// ---------------- prep: split B' (=W transposed) into bf16 hi/lo planes + zero scratch ----
__global__ __launch_bounds__(256) void prep_k(const float* __restrict__ W_heads,
                                              ushort* __restrict__ bth,
                                              ushort* __restrict__ btl,
                                              float* __restrict__ zbase,
                                              int zcount) {
  int gid = blockIdx.x * 256 + threadIdx.x;
  int n = gid >> 9, c = gid & 511;
  int h = n >> 6, f = n & 63;
  float w = W_heads[((size_t)h * NFEAT + c) * NHID + f];
  ushort hh = f2b(w);
  bth[gid] = hh;
  btl[gid] = f2b(w - b2f(hh));
  if (gid < zcount) zbase[gid] = 0.f;  // zero mm/meanS region
}

// ---------------- GEMM1: Wh(fp32) = x @ B' via split-bf16 MFMA (3 terms), 128x128 tiles ----
__global__ __launch_bounds__(256) void gemm1_k(const float* __restrict__ x,
                                               const ushort* __restrict__ bth,
                                               const ushort* __restrict__ btl,
                                               const float* __restrict__ a_heads,
                                               float* __restrict__ Wh,
                                               float* __restrict__ f1,
                                               float* __restrict__ f2,
                                               float* __restrict__ meanS,
                                               uint* __restrict__ mm1) {
  const int row0 = blockIdx.x * 128, col0 = blockIdx.y * 128;
  const int tid = threadIdx.x;
  const int wave = tid >> 6, lane = tid & 63;
  const int wr = wave >> 1, wc = wave & 1;
  __shared__ ushort Ah[128 * 40], Al[128 * 40], Bh[128 * 40], Bl[128 * 40];
  __shared__ float cs[2][64];
  __shared__ uint lmax[2], lmin[2];
  if (tid < 2) { lmax[tid] = 0u; lmin[tid] = 0u; }
  if (tid < 128) cs[tid >> 6][tid & 63] = 0.f;
  f32x4 acc[4][4] = {};
  const int sr = tid >> 1, sh = (tid & 1) * 16;
  const int fr = lane & 15, quad = lane >> 4;
  for (int k0 = 0; k0 < NFEAT; k0 += 32) {
    {
      const float* xs = x + (size_t)(row0 + sr) * NFEAT + k0 + sh;
      float av[16];
      *reinterpret_cast<float4*>(&av[0])  = *reinterpret_cast<const float4*>(xs);
      *reinterpret_cast<float4*>(&av[4])  = *reinterpret_cast<const float4*>(xs + 4);
      *reinterpret_cast<float4*>(&av[8])  = *reinterpret_cast<const float4*>(xs + 8);
      *reinterpret_cast<float4*>(&av[12]) = *reinterpret_cast<const float4*>(xs + 12);
      uint uh[8], ul[8];
#pragma unroll
      for (int q = 0; q < 8; ++q) {
        ushort h0 = f2b(av[2 * q]), h1 = f2b(av[2 * q + 1]);
        ushort l0 = f2b(av[2 * q] - b2f(h0)), l1 = f2b(av[2 * q + 1] - b2f(h1));
        uh[q] = (uint)h0 | ((uint)h1 << 16);
        ul[q] = (uint)l0 | ((uint)l1 << 16);
      }
      *reinterpret_cast<uint4*>(&Ah[sr * 40 + sh])     = make_uint4(uh[0], uh[1], uh[2], uh[3]);
      *reinterpret_cast<uint4*>(&Ah[sr * 40 + sh + 8]) = make_uint4(uh[4], uh[5], uh[6], uh[7]);
      *reinterpret_cast<uint4*>(&Al[sr * 40 + sh])     = make_uint4(ul[0], ul[1], ul[2], ul[3]);
      *reinterpret_cast<uint4*>(&Al[sr * 40 + sh + 8]) = make_uint4(ul[4], ul[5], ul[6], ul[7]);
      size_t boff = (size_t)(col0 + sr) * NFEAT + k0 + sh;
      *reinterpret_cast<uint4*>(&Bh[sr * 40 + sh])     = *reinterpret_cast<const uint4*>(bth + boff);
      *reinterpret_cast<uint4*>(&Bh[sr * 40 + sh + 8]) = *reinterpret_cast<const uint4*>(bth + boff + 8);
      *reinterpret_cast<uint4*>(&Bl[sr * 40 + sh])     = *reinterpret_cast<const uint4*>(btl + boff);
      *reinterpret_cast<uint4*>(&Bl[sr * 40 + sh + 8]) = *reinterpret_cast<const uint4*>(btl + boff + 8);
    }
    __syncthreads();
    bf16x8 afh[4], afl[4], bfh[4], bfl[4];
#pragma unroll
    for (int q = 0; q < 4; ++q) {
      afh[q] = *reinterpret_cast<const bf16x8*>(&Ah[(wr * 64 + q * 16 + fr) * 40 + quad * 8]);
      afl[q] = *reinterpret_cast<const bf16x8*>(&Al[(wr * 64 + q * 16 + fr) * 40 + quad * 8]);
      bfh[q] = *reinterpret_cast<const bf16x8*>(&Bh[(wc * 64 + q * 16 + fr) * 40 + quad * 8]);
      bfl[q] = *reinterpret_cast<const bf16x8*>(&Bl[(wc * 64 + q * 16 + fr) * 40 + quad * 8]);
    }
#pragma unroll
    for (int qr = 0; qr < 4; ++qr)
#pragma unroll
      for (int qc = 0; qc < 4; ++qc) {
        acc[qr][qc] = __builtin_amdgcn_mfma_f32_16x16x32_bf16(afl[qr], bfh[qc], acc[qr][qc], 0, 0, 0);
        acc[qr][qc] = __builtin_amdgcn_mfma_f32_16x16x32_bf16(afh[qr], bfl[qc], acc[qr][qc], 0, 0, 0);
        acc[qr][qc] = __builtin_amdgcn_mfma_f32_16x16x32_bf16(afh[qr], bfh[qc], acc[qr][qc], 0, 0, 0);
      }
    __syncthreads();
  }
  const int head = blockIdx.y * 2 + wc;
#pragma unroll
  for (int qr = 0; qr < 4; ++qr)
#pragma unroll
    for (int qc = 0; qc < 4; ++qc)
#pragma unroll
      for (int i = 0; i < 4; ++i) {
        int row = row0 + wr * 64 + qr * 16 + quad * 4 + i;
        int col = col0 + wc * 64 + qc * 16 + fr;
        Wh[(size_t)row * NFEAT + col] = acc[qr][qc][i];
      }
  const float* ah = a_heads + head * 2 * NHID;
  float a1v[4], a2v[4];
#pragma unroll
  for (int qc = 0; qc < 4; ++qc) { a1v[qc] = ah[qc * 16 + fr]; a2v[qc] = ah[NHID + qc * 16 + fr]; }
#pragma unroll
  for (int qr = 0; qr < 4; ++qr)
#pragma unroll
    for (int i = 0; i < 4; ++i) {
      float s1 = 0.f, s2 = 0.f;
#pragma unroll
      for (int qc = 0; qc < 4; ++qc) { s1 += acc[qr][qc][i] * a1v[qc]; s2 += acc[qr][qc][i] * a2v[qc]; }
#pragma unroll
      for (int m = 1; m < 16; m <<= 1) { s1 += __shfl_xor(s1, m, 64); s2 += __shfl_xor(s2, m, 64); }
      if (fr == 0) {
        int row = row0 + wr * 64 + qr * 16 + quad * 4 + i;
        f1[(head << 13) + row] = s1;
        f2[(head << 13) + row] = s2;
        atomicMax(&lmax[wc], encf(s2));
        atomicMax(&lmin[wc], ~encf(s2));
      }
    }
#pragma unroll
  for (int qc = 0; qc < 4; ++qc) {
    float v = 0.f;
#pragma unroll
    for (int qr = 0; qr < 4; ++qr)
#pragma unroll
      for (int i = 0; i < 4; ++i) v += acc[qr][qc][i];
    v += __shfl_xor(v, 16, 64);
    v += __shfl_xor(v, 32, 64);
    if (quad == 0) atomicAdd(&cs[wc][qc * 16 + fr], v);
  }
  __syncthreads();
  if (tid < 128) atomicAdd(&meanS[(blockIdx.y * 2 + (tid >> 6)) * NHID + (tid & 63)], cs[tid >> 6][tid & 63]);
  if (tid < 2) {
    atomicMax(&mm1[(blockIdx.y * 2 + tid) * 2], lmax[tid]);
    atomicMax(&mm1[(blockIdx.y * 2 + tid) * 2 + 1], lmin[tid]);
  }
}

// ---------------- GEMM2 fused: Wh2 = H @ W_out + f1b/f2b + colsums + minmax ----------------
__global__ __launch_bounds__(256) void gemm2_k(const float* __restrict__ H,
                                               const float* __restrict__ Wout,
                                               const float* __restrict__ a_out,
                                               float* __restrict__ Wh2,
                                               float* __restrict__ f1b,
                                               float* __restrict__ f2b,
                                               float* __restrict__ meanS2,
                                               uint* __restrict__ mm2) {
  const int row0 = blockIdx.x * 32;
  const int tid = threadIdx.x;
  __shared__ float As[32][33];
  __shared__ float Bs[32][40];
  __shared__ float cs[NCLASS];
  __shared__ uint lmax, lmin;
  if (tid < NCLASS) cs[tid] = 0.f;
  if (tid == 0) { lmax = 0u; lmin = 0u; }
  const int m = tid >> 3;
  const int n0 = (tid & 7) * 5;
  float acc[5] = {};
  for (int k0 = 0; k0 < NFEAT; k0 += 32) {
    {
      int kk = tid & 31, mq = tid >> 5;
#pragma unroll
      for (int r = 0; r < 4; ++r)
        As[kk][mq * 4 + r] = H[(size_t)(row0 + mq * 4 + r) * NFEAT + k0 + kk];
    }
    {
#pragma unroll
      for (int r = 0; r < 5; ++r) {
        int idx = tid + r * 256;
        if (idx < 1280) {
          int c = idx / 40, n = idx - c * 40;
          Bs[c][n] = Wout[(size_t)(k0 + c) * NCLASS + n];
        }
      }
    }
    __syncthreads();
#pragma unroll
    for (int kk = 0; kk < 32; ++kk) {
      float a = As[kk][m];
#pragma unroll
      for (int q = 0; q < 5; ++q) acc[q] += a * Bs[kk][n0 + q];
    }
    __syncthreads();
  }
#pragma unroll
  for (int q = 0; q < 5; ++q) Wh2[(size_t)(row0 + m) * NCLASS + n0 + q] = acc[q];
  float p1 = 0.f, p2 = 0.f;
#pragma unroll
  for (int q = 0; q < 5; ++q) {
    p1 += acc[q] * a_out[n0 + q];
    p2 += acc[q] * a_out[NCLASS + n0 + q];
  }
  p1 += __shfl_xor(p1, 1, 64); p1 += __shfl_xor(p1, 2, 64); p1 += __shfl_xor(p1, 4, 64);
  p2 += __shfl_xor(p2, 1, 64); p2 += __shfl_xor(p2, 2, 64); p2 += __shfl_xor(p2, 4, 64);
  if ((tid & 7) == 0) {
    f1b[row0 + m] = p1;
    f2b[row0 + m] = p2;
    atomicMax(&lmax, encf(p2));
    atomicMax(&lmin, ~encf(p2));
  }
#pragma unroll
  for (int q = 0; q < 5; ++q) atomicAdd(&cs[n0 + q], acc[q]);
  __syncthreads();
  if (tid < NCLASS) atomicAdd(&meanS2[tid], cs[tid]);
  if (tid == 0) { atomicMax(&mm2[0], lmax); atomicMax(&mm2[1], lmin); }
}

// ---------------- bucket: hist + prefix + scatter in one kernel, one block per head ----------
__global__ __launch_bounds__(1024) void bucket_k(const float* __restrict__ f2,
                                                 const uint* __restrict__ mm,
                                                 int* __restrict__ bs,
                                                 int* __restrict__ idxs,
                                                 float* __restrict__ f2s,
                                                 float* __restrict__ g) {
  __shared__ int sb[NB];
  const int head = blockIdx.x, tid = threadIdx.x;
  const int base = head * N_NODES;
  float3 rg = load_rng(mm, head);
#pragma unroll
  for (int r = 0; r < NB / 1024; ++r) sb[tid + r * 1024] = 0;
  __syncthreads();
  float v[8];
  int bk[8];
#pragma unroll
  for (int r = 0; r < 8; ++r) {
    v[r] = f2[base + tid + r * 1024];
    bk[r] = bucket_of(v[r], rg.x, rg.y);
    atomicAdd(&sb[bk[r]], 1);
  }
  __syncthreads();
  for (int st = 1; st < NB; st <<= 1) {
    int t[NB / 1024];
#pragma unroll
    for (int r = 0; r < NB / 1024; ++r) { int i = tid + r * 1024; t[r] = (i >= st) ? sb[i - st] : 0; }
    __syncthreads();
#pragma unroll
    for (int r = 0; r < NB / 1024; ++r) sb[tid + r * 1024] += t[r];
    __syncthreads();
  }
  int ex[NB / 1024];
#pragma unroll
  for (int r = 0; r < NB / 1024; ++r) {
    int b = tid + r * 1024;
    ex[r] = b ? sb[b - 1] : 0;
    bs[head * (NB + 1) + b] = ex[r];
  }
  if (tid == 0) bs[head * (NB + 1) + NB] = sb[NB - 1];
  __syncthreads();
#pragma unroll
  for (int r = 0; r < NB / 1024; ++r) sb[tid + r * 1024] = ex[r];
  __syncthreads();
#pragma unroll
  for (int r = 0; r < 8; ++r) {
    int pos = atomicAdd(&sb[bk[r]], 1);
    int i = tid + r * 1024;
    idxs[base + pos] = i;
    f2s[base + pos] = v[r];
    g[base + pos] = expf(v[r] - rg.z);
  }
}

// ---------------- suffix scan phase A: one 256-thread block per chunk, 4 waves x 16 elems ----
template <int F, int LD, int COLSTEP>
__global__ __launch_bounds__(256) void scanA_k(const float* __restrict__ Wh,
                                               const float* __restrict__ g,
                                               const int* __restrict__ idxs,
                                               float* __restrict__ S,
                                               float* __restrict__ D,
                                               float* __restrict__ T_,
                                               float* __restrict__ Td) {
  constexpr int PAD = (F == 64) ? 66 : 42;
  const int head = blockIdx.y, chunk = blockIdx.x;
  const int tid = threadIdx.x, w = tid >> 6, lane = tid & 63;
  const int base = head << 13;
  const int kbase = base + chunk * CHUNK;
  __shared__ float Sloc[64][PAD];
  __shared__ float Dloc[64];
  __shared__ float wtot[4][PAD];
  __shared__ float wtotD[4];
  int myj = 0; float myg = 0.f;
  if (lane < 16) {
    myj = idxs[kbase + w * 16 + lane];
    myg = g[kbase + w * 16 + lane];
  }
  float acc = 0.f, accD = 0.f;
#pragma unroll
  for (int kk = 15; kk >= 0; --kk) {
    int j = __shfl(myj, kk, 64);
    float gk = __shfl(myg, kk, 64);
    float wv = (lane < F) ? Wh[(size_t)j * LD + head * COLSTEP + lane] : 0.f;
    acc += gk * wv;
    accD += gk;
    if (lane < F) Sloc[w * 16 + kk][lane] = acc;
    if (lane == 0) Dloc[w * 16 + kk] = accD;
  }
  if (lane < F) wtot[w][lane] = acc;
  if (lane == 0) wtotD[w] = accD;
  __syncthreads();
  float off = 0.f, offD = 0.f;
#pragma unroll
  for (int w2 = 1; w2 < 4; ++w2) {
    if (w + w2 < 4) {
      off += (lane < F) ? wtot[w + w2][lane] : 0.f;
      offD += wtotD[w + w2];
    }
  }
#pragma unroll
  for (int kk = 0; kk < 16; ++kk) {
    int e = w * 16 + kk;
    if (lane < F) S[(size_t)(kbase + e) * F + lane] = Sloc[e][lane] + off;
    if (lane == 0) D[kbase + e] = Dloc[e] + offD;
  }
  if (w == 0) {
    if (lane < F) T_[(size_t)(head * NCHUNK + chunk) * F + lane] = wtot[0][lane] + off;
    if (lane == 0) Td[head * NCHUNK + chunk] = wtotD[0] + offD;
  }
}

// ---------------- suffix scan phase B: LDS Hillis-Steele over chunk totals (1024 thr) --------
template <int F>
__global__ __launch_bounds__(1024) void scanB_k(float* __restrict__ T_, float* __restrict__ Td) {
  __shared__ float s[NCHUNK * F];
  __shared__ float td[NCHUNK];
  int head = blockIdx.x;
  int tid = threadIdx.x, slot = tid >> 6, lane = tid & 63;
#pragma unroll
  for (int r = 0; r < 8; ++r) {
    int c = r * 16 + slot;
    if (lane < F) s[c * F + lane] = T_[(size_t)(head * NCHUNK + c) * F + lane];
  }
  if (tid < NCHUNK) td[tid] = Td[head * NCHUNK + tid];
  __syncthreads();
  for (int st = 1; st < NCHUNK; st <<= 1) {
    float v[8];
    float tv = 0.f;
#pragma unroll
    for (int r = 0; r < 8; ++r) {
      int c = r * 16 + slot;
      v[r] = (lane < F && c + st < NCHUNK) ? s[(c + st) * F + lane] : 0.f;
    }
    if (tid < NCHUNK && tid + st < NCHUNK) tv = td[tid + st];
    __syncthreads();
#pragma unroll
    for (int r = 0; r < 8; ++r) {
      int c = r * 16 + slot;
      if (lane < F) s[c * F + lane] += v[r];
    }
    if (tid < NCHUNK) td[tid] += tv;
    __syncthreads();
  }
#pragma unroll
  for (int r = 0; r < 8; ++r) {
    int c = r * 16 + slot;
    if (lane < F) T_[(size_t)(head * NCHUNK + c) * F + lane] = s[c * F + lane];
  }
  if (tid < NCHUNK) Td[head * NCHUNK + tid] = td[tid];
}

// ---------------- layer-1 queries ----------------
__global__ __launch_bounds__(256) void query1_k(const float* __restrict__ f1,
                                                const float* __restrict__ f2s,
                                                const int* __restrict__ idxs,
                                                const float* __restrict__ Wh,
                                                const float* __restrict__ S,
                                                const float* __restrict__ D,
                                                const float* __restrict__ T_,
                                                const float* __restrict__ Td,
                                                const uint* __restrict__ mm,
                                                const int* __restrict__ bs,
                                                const float* __restrict__ meanS,
                                                float* __restrict__ H) {
  int w = blockIdx.x * 4 + (threadIdx.x >> 6);
  int lane = threadIdx.x & 63;
  int head = w & 7, i = w >> 3, base = head << 13;
  float t = f1[base + i];
  float3 rg = load_rng(mm, head);
  int B0 = bucket_of(-t, rg.x, rg.y);
  int p0 = bs[head * (NB + 1) + B0], p1 = bs[head * (NB + 1) + B0 + 1];
  float num = 0.f, den = 0.f;
  int cnt = N_NODES - p1;
  if (p1 < N_NODES) {
    int c = p1 >> 6;
    num = S[(size_t)(base + p1) * NHID + lane] +
          ((c + 1 < NCHUNK) ? T_[(size_t)(head * NCHUNK + c + 1) * NHID + lane] : 0.f);
    den = D[base + p1] + ((c + 1 < NCHUNK) ? Td[head * NCHUNK + c + 1] : 0.f);
  }
  for (int p = p0; p < p1; ++p) {
    float v = f2s[base + p];
    if (t + v > 0.f) {
      int j = idxs[base + p];
      float gk = expf(v - rg.z);
      num += gk * Wh[(size_t)j * NFEAT + head * NHID + lane];
      den += gk;
      ++cnt;
    }
  }
  float val = cnt ? num / den : meanS[head * NHID + lane] * (1.f / N_NODES);
  H[(size_t)i * NFEAT + head * NHID + lane] = (val > 0.f) ? val : expm1f(val);
}

// ---------------- layer-2 queries + elu + log_softmax ----------------
__global__ __launch_bounds__(256) void final_k(const float* __restrict__ f1b,
                                               const float* __restrict__ f2bs,
                                               const int* __restrict__ idx2,
                                               const float* __restrict__ Wh2,
                                               const float* __restrict__ S2,
                                               const float* __restrict__ D2,
                                               const float* __restrict__ T2,
                                               const float* __restrict__ Td2,
                                               const uint* __restrict__ mm2,
                                               const int* __restrict__ bs2,
                                               const float* __restrict__ meanS2,
                                               float* __restrict__ out) {
  int i = blockIdx.x * 4 + (threadIdx.x >> 6);
  int lane = threadIdx.x & 63;
  float t = f1b[i];
  float3 rg = load_rng(mm2, 0);
  int B0 = bucket_of(-t, rg.x, rg.y);
  int p0 = bs2[B0], p1 = bs2[B0 + 1];
  float num = 0.f, den = 0.f;
  int cnt = N_NODES - p1;
  if (p1 < N_NODES) {
    int c = p1 >> 6;
    num = (lane < NCLASS) ? (S2[(size_t)p1 * NCLASS + lane] +
                             ((c + 1 < NCHUNK) ? T2[(size_t)(c + 1) * NCLASS + lane] : 0.f))
                          : 0.f;
    den = D2[p1] + ((c + 1 < NCHUNK) ? Td2[c + 1] : 0.f);
  }
  for (int p = p0; p < p1; ++p) {
    float v = f2bs[p];
    if (t + v > 0.f) {
      int j = idx2[p];
      float gk = expf(v - rg.z);
      if (lane < NCLASS) num += gk * Wh2[(size_t)j * NCLASS + lane];
      den += gk;
      ++cnt;
    }
  }
  float o;
  if (lane < NCLASS) {
    float val = cnt ? num / den : meanS2[lane] * (1.f / N_NODES);
    o = (val > 0.f) ? val : expm1f(val);
  } else {
    o = -INFINITY;
  }
  float m = o;
#pragma unroll
  for (int msk = 32; msk; msk >>= 1) m = fmaxf(m, __shfl_xor(m, msk, 64));
  float e = (lane < NCLASS) ? expf(o - m) : 0.f;
#pragma unroll
  for (int msk = 32; msk; msk >>= 1) e += __shfl_xor(e, msk, 64);
  if (lane < NCLASS) out[(size_t)i * NCLASS + lane] = o - m - logf(e);
}

extern "C" void kernel_launch(void* const* d_in, const int* in_sizes, int n_in,
                              void* d_out, int out_size, void* d_ws, size_t ws_size,
                              hipStream_t stream) {
  const float* x       = (const float*)d_in[0];
  const float* W_heads = (const float*)d_in[2];
  const float* a_heads = (const float*)d_in[3];
  const float* W_out   = (const float*)d_in[4];
  const float* a_out   = (const float*)d_in[5];
  float* out = (float*)d_out;

  float* ws = (float*)d_ws;
  size_t o = 0;
  auto alloc = [&](size_t n) { float* p = ws + o; o += (n + 3) & ~(size_t)3; return p; };
  float*  S1     = alloc((size_t)NHEADS * N_NODES * NHID);   // 16 MB
  ushort* BTh    = (ushort*)alloc((size_t)NFEAT * NFEAT / 2);
  ushort* BTl    = (ushort*)alloc((size_t)NFEAT * NFEAT / 2);
  float*  Wh     = alloc((size_t)N_NODES * NFEAT);           // 16 MB fp32
  float*  H      = alloc((size_t)N_NODES * NFEAT);           // 16 MB
  float*  f1     = alloc(NHEADS * N_NODES);
  float*  f2     = alloc(NHEADS * N_NODES);
  float*  f2s    = alloc(NHEADS * N_NODES);
  int*    idxs   = (int*)alloc(NHEADS * N_NODES);
  float*  g1     = alloc(NHEADS * N_NODES);
  float*  D1     = alloc(NHEADS * N_NODES);
  float*  T1     = alloc(NHEADS * NCHUNK * NHID);
  float*  Td1    = alloc(NHEADS * NCHUNK);
  int*    bst1   = (int*)alloc(NHEADS * (NB + 1));
  float*  Wh2    = alloc((size_t)N_NODES * NCLASS);
  float*  S2     = alloc((size_t)N_NODES * NCLASS);
  float*  f1b    = alloc(N_NODES);
  float*  f2b    = alloc(N_NODES);
  float*  f2bs   = alloc(N_NODES);
  int*    idx2   = (int*)alloc(N_NODES);
  float*  g2     = alloc(N_NODES);
  float*  D2     = alloc(N_NODES);
  float*  T2     = alloc(NCHUNK * NCLASS);
  float*  Td2    = alloc(NCHUNK);
  int*    bst2   = (int*)alloc(NB + 1);
  // ---- contiguous zero region (zeroed by prep_k) ----
  float*  zbase  = ws + o;
  uint*   mm1    = (uint*)alloc(16);
  uint*   mm2    = (uint*)alloc(4);
  float*  meanS1 = alloc(NHEADS * NHID);
  float*  meanS2 = alloc(64);
  int zcount = (int)((ws + o) - zbase);

  // ---- layer 1 ----
  prep_k<<<1024, 256, 0, stream>>>(W_heads, BTh, BTl, zbase, zcount);
  gemm1_k<<<dim3(64, 4), 256, 0, stream>>>(x, BTh, BTl, a_heads, Wh, f1, f2, meanS1, mm1);
  bucket_k<<<NHEADS, 1024, 0, stream>>>(f2, mm1, bst1, idxs, f2s, g1);
  scanA_k<NHID, NFEAT, NHID><<<dim3(NCHUNK, NHEADS), 256, 0, stream>>>(Wh, g1, idxs, S1, D1, T1, Td1);
  scanB_k<NHID><<<NHEADS, 1024, 0, stream>>>(T1, Td1);
  query1_k<<<16384, 256, 0, stream>>>(f1, f2s, idxs, Wh, S1, D1, T1, Td1, mm1, bst1, meanS1, H);

  // ---- layer 2 ----
  gemm2_k<<<256, 256, 0, stream>>>(H, W_out, a_out, Wh2, f1b, f2b, meanS2, mm2);
  bucket_k<<<1, 1024, 0, stream>>>(f2b, mm2, bst2, idx2, f2bs, g2);
  scanA_k<NCLASS, NCLASS, 0><<<dim3(NCHUNK, 1), 256, 0, stream>>>(Wh2, g2, idx2, S2, D2, T2, Td2);
  scanB_k<NCLASS><<<1, 1024, 0, stream>>>(T2, Td2);
  final_k<<<2048, 256, 0, stream>>>(f1b, f2bs, idx2, Wh2, S2, D2, T2, Td2, mm2, bst2, meanS2, out);
}

// Round 9
// 498.401 us; speedup vs baseline: 1.3864x; 1.0768x over previous
//
#include <hip/hip_runtime.h>
#include <math.h>

#define N_NODES 8192
#define NFEAT 512
#define NHID 64
#define NHEADS 8
#define NCLASS 40
#define NCHUNK 128
#define CHUNK 64
#define NB 4096

using bf16x8 = __attribute__((ext_vector_type(8))) short;
using f32x4 = __attribute__((ext_vector_type(4))) float;

// ---- helpers ----
__device__ __forceinline__ ushort f2b(float f) {  // fp32 -> bf16 RNE
  uint u = __builtin_bit_cast(uint, f);
  u += 0x7FFFu + ((u >> 16) & 1u);
  return (ushort)(u >> 16);
}
__device__ __forceinline__ float b2f(ushort h) {
  uint u = (uint)h << 16;
  return __builtin_bit_cast(float, u);
}
__device__ __forceinline__ uint encf(float f) {  // sortable-ascending uint
  uint u = __builtin_bit_cast(uint, f);
  return u ^ ((u >> 31) ? 0xFFFFFFFFu : 0x80000000u);
}
__device__ __forceinline__ float decf(uint u) {
  u ^= ((u >> 31) ? 0x80000000u : 0xFFFFFFFFu);
  return __builtin_bit_cast(float, u);
}
__device__ __forceinline__ float3 load_rng(const uint* mm, int head) {
  float h = decf(mm[head * 2]);
  float l = decf(~mm[head * 2 + 1]);
  float scale = (float)NB / fmaxf(h - l, 1e-30f);
  return make_float3(l, scale, h);
}
__device__ __forceinline__ int bucket_of(float v, float lo, float scale) {
  float u = fminf(fmaxf((v - lo) * scale, 0.f), (float)(NB - 1));
  return (int)u;
}

// ---------------- prep: split B1'=W^T and B2'=Wout^T (pad 48) into bf16 hi/lo + zero scratch --
__global__ __launch_bounds__(256) void prep_k(const float* __restrict__ W_heads,
                                              const float* __restrict__ Wout,
                                              ushort* __restrict__ bth,
                                              ushort* __restrict__ btl,
                                              ushort* __restrict__ bt2h,
                                              ushort* __restrict__ bt2l,
                                              float* __restrict__ zbase,
                                              int zcount) {
  int b = blockIdx.x, t = threadIdx.x;
  if (b < 1024) {
    int gid = b * 256 + t;
    int n = gid >> 9, c = gid & 511;
    int h = n >> 6, f = n & 63;
    float w = W_heads[((size_t)h * NFEAT + c) * NHID + f];
    ushort hh = f2b(w);
    bth[gid] = hh;
    btl[gid] = f2b(w - b2f(hh));
    if (gid < zcount) zbase[gid] = 0.f;
  } else {
    int gid = (b - 1024) * 256 + t;   // 0..24575 : BT2[n][c], n=0..47 (pad>=40), c=0..511
    int n = gid >> 9, c = gid & 511;
    float w = (n < NCLASS) ? Wout[(size_t)c * NCLASS + n] : 0.f;
    ushort hh = f2b(w);
    bt2h[gid] = hh;
    bt2l[gid] = f2b(w - b2f(hh));
  }
}

// ---------------- GEMM1: Wh(fp32) = x @ B' via split-bf16 MFMA, 128x128 tiles, LDS dbuf ------
// grid (4 cols, 64 rows): col varies fastest -> x-tile L2 reuse.
__global__ __launch_bounds__(256) void gemm1_k(const float* __restrict__ x,
                                               const ushort* __restrict__ bth,
                                               const ushort* __restrict__ btl,
                                               const float* __restrict__ a_heads,
                                               float* __restrict__ Wh,
                                               float* __restrict__ f1,
                                               float* __restrict__ f2,
                                               float* __restrict__ meanS,
                                               uint* __restrict__ mm1) {
  const int col0 = blockIdx.x * 128, row0 = blockIdx.y * 128;
  const int tid = threadIdx.x;
  const int wave = tid >> 6, lane = tid & 63;
  const int wr = wave >> 1, wc = wave & 1;
  __shared__ ushort Ah[2][128 * 40], Al[2][128 * 40], Bh[2][128 * 40], Bl[2][128 * 40];
  __shared__ float cs[2][64];
  __shared__ uint lmax[2], lmin[2];
  if (tid < 2) { lmax[tid] = 0u; lmin[tid] = 0u; }
  if (tid < 128) cs[tid >> 6][tid & 63] = 0.f;
  f32x4 acc[4][4] = {};
  const int sr = tid >> 1, sh = (tid & 1) * 16;
  const int fr = lane & 15, quad = lane >> 4;

  float av[16];
  uint4 bh0, bh1, bl0, bl1;
  auto load_tile = [&](int k0) {
    const float* xs = x + (size_t)(row0 + sr) * NFEAT + k0 + sh;
    *reinterpret_cast<float4*>(&av[0])  = *reinterpret_cast<const float4*>(xs);
    *reinterpret_cast<float4*>(&av[4])  = *reinterpret_cast<const float4*>(xs + 4);
    *reinterpret_cast<float4*>(&av[8])  = *reinterpret_cast<const float4*>(xs + 8);
    *reinterpret_cast<float4*>(&av[12]) = *reinterpret_cast<const float4*>(xs + 12);
    size_t boff = (size_t)(col0 + sr) * NFEAT + k0 + sh;
    bh0 = *reinterpret_cast<const uint4*>(bth + boff);
    bh1 = *reinterpret_cast<const uint4*>(bth + boff + 8);
    bl0 = *reinterpret_cast<const uint4*>(btl + boff);
    bl1 = *reinterpret_cast<const uint4*>(btl + boff + 8);
  };
  auto store_tile = [&](int buf) {
    uint uh[8], ul[8];
#pragma unroll
    for (int q = 0; q < 8; ++q) {
      ushort h0 = f2b(av[2 * q]), h1 = f2b(av[2 * q + 1]);
      ushort l0 = f2b(av[2 * q] - b2f(h0)), l1 = f2b(av[2 * q + 1] - b2f(h1));
      uh[q] = (uint)h0 | ((uint)h1 << 16);
      ul[q] = (uint)l0 | ((uint)l1 << 16);
    }
    *reinterpret_cast<uint4*>(&Ah[buf][sr * 40 + sh])     = make_uint4(uh[0], uh[1], uh[2], uh[3]);
    *reinterpret_cast<uint4*>(&Ah[buf][sr * 40 + sh + 8]) = make_uint4(uh[4], uh[5], uh[6], uh[7]);
    *reinterpret_cast<uint4*>(&Al[buf][sr * 40 + sh])     = make_uint4(ul[0], ul[1], ul[2], ul[3]);
    *reinterpret_cast<uint4*>(&Al[buf][sr * 40 + sh + 8]) = make_uint4(ul[4], ul[5], ul[6], ul[7]);
    *reinterpret_cast<uint4*>(&Bh[buf][sr * 40 + sh])     = bh0;
    *reinterpret_cast<uint4*>(&Bh[buf][sr * 40 + sh + 8]) = bh1;
    *reinterpret_cast<uint4*>(&Bl[buf][sr * 40 + sh])     = bl0;
    *reinterpret_cast<uint4*>(&Bl[buf][sr * 40 + sh + 8]) = bl1;
  };

  load_tile(0);
  store_tile(0);
  for (int it = 0; it < 16; ++it) {
    const int buf = it & 1;
    if (it < 15) load_tile((it + 1) * 32);   // in flight during MFMA
    __syncthreads();                          // LDS[buf] ready
    bf16x8 afh[4], afl[4], bfh[4], bfl[4];
#pragma unroll
    for (int q = 0; q < 4; ++q) {
      afh[q] = *reinterpret_cast<const bf16x8*>(&Ah[buf][(wr * 64 + q * 16 + fr) * 40 + quad * 8]);
      afl[q] = *reinterpret_cast<const bf16x8*>(&Al[buf][(wr * 64 + q * 16 + fr) * 40 + quad * 8]);
      bfh[q] = *reinterpret_cast<const bf16x8*>(&Bh[buf][(wc * 64 + q * 16 + fr) * 40 + quad * 8]);
      bfl[q] = *reinterpret_cast<const bf16x8*>(&Bl[buf][(wc * 64 + q * 16 + fr) * 40 + quad * 8]);
    }
#pragma unroll
    for (int qr = 0; qr < 4; ++qr)
#pragma unroll
      for (int qc = 0; qc < 4; ++qc) {
        acc[qr][qc] = __builtin_amdgcn_mfma_f32_16x16x32_bf16(afl[qr], bfh[qc], acc[qr][qc], 0, 0, 0);
        acc[qr][qc] = __builtin_amdgcn_mfma_f32_16x16x32_bf16(afh[qr], bfl[qc], acc[qr][qc], 0, 0, 0);
        acc[qr][qc] = __builtin_amdgcn_mfma_f32_16x16x32_bf16(afh[qr], bfh[qc], acc[qr][qc], 0, 0, 0);
      }
    if (it < 15) store_tile(buf ^ 1);         // write next buffer; barrier at loop top protects
  }
  const int head = blockIdx.x * 2 + wc;
#pragma unroll
  for (int qr = 0; qr < 4; ++qr)
#pragma unroll
    for (int qc = 0; qc < 4; ++qc)
#pragma unroll
      for (int i = 0; i < 4; ++i) {
        int row = row0 + wr * 64 + qr * 16 + quad * 4 + i;
        int col = col0 + wc * 64 + qc * 16 + fr;
        Wh[(size_t)row * NFEAT + col] = acc[qr][qc][i];
      }
  const float* ah = a_heads + head * 2 * NHID;
  float a1v[4], a2v[4];
#pragma unroll
  for (int qc = 0; qc < 4; ++qc) { a1v[qc] = ah[qc * 16 + fr]; a2v[qc] = ah[NHID + qc * 16 + fr]; }
#pragma unroll
  for (int qr = 0; qr < 4; ++qr)
#pragma unroll
    for (int i = 0; i < 4; ++i) {
      float s1 = 0.f, s2 = 0.f;
#pragma unroll
      for (int qc = 0; qc < 4; ++qc) { s1 += acc[qr][qc][i] * a1v[qc]; s2 += acc[qr][qc][i] * a2v[qc]; }
#pragma unroll
      for (int m = 1; m < 16; m <<= 1) { s1 += __shfl_xor(s1, m, 64); s2 += __shfl_xor(s2, m, 64); }
      if (fr == 0) {
        int row = row0 + wr * 64 + qr * 16 + quad * 4 + i;
        f1[(head << 13) + row] = s1;
        f2[(head << 13) + row] = s2;
        atomicMax(&lmax[wc], encf(s2));
        atomicMax(&lmin[wc], ~encf(s2));
      }
    }
#pragma unroll
  for (int qc = 0; qc < 4; ++qc) {
    float v = 0.f;
#pragma unroll
    for (int qr = 0; qr < 4; ++qr)
#pragma unroll
      for (int i = 0; i < 4; ++i) v += acc[qr][qc][i];
    v += __shfl_xor(v, 16, 64);
    v += __shfl_xor(v, 32, 64);
    if (quad == 0) atomicAdd(&cs[wc][qc * 16 + fr], v);
  }
  __syncthreads();
  if (tid < 128) atomicAdd(&meanS[(blockIdx.x * 2 + (tid >> 6)) * NHID + (tid & 63)], cs[tid >> 6][tid & 63]);
  if (tid < 2) {
    atomicMax(&mm1[(blockIdx.x * 2 + tid) * 2], lmax[tid]);
    atomicMax(&mm1[(blockIdx.x * 2 + tid) * 2 + 1], lmin[tid]);
  }
}

// ---------------- GEMM2: Wh2 = H @ Wout via split-bf16 MFMA, 128x40 tiles + fused epilogue ---
__global__ __launch_bounds__(256) void gemm2_k(const float* __restrict__ H,
                                               const ushort* __restrict__ bt2h,
                                               const ushort* __restrict__ bt2l,
                                               const float* __restrict__ a_out,
                                               float* __restrict__ Wh2,
                                               float* __restrict__ f1bv,
                                               float* __restrict__ f2bv,
                                               float* __restrict__ meanS2,
                                               uint* __restrict__ mm2) {
  const int row0 = blockIdx.x * 128;
  const int tid = threadIdx.x;
  const int w = tid >> 6, lane = tid & 63;
  const int fr = lane & 15, quad = lane >> 4;
  __shared__ ushort Ah[128 * 40], Al[128 * 40];   // 128 rows x 32 k (pad 40)
  __shared__ ushort Bh[48 * 40], Bl[48 * 40];     // 48 n x 32 k (pad 40)
  __shared__ float cs[48];
  __shared__ uint lmax, lmin;
  if (tid < 48) cs[tid] = 0.f;
  if (tid == 0) { lmax = 0u; lmin = 0u; }
  f32x4 acc[2][3] = {};
  const int sr = tid >> 1, sh = (tid & 1) * 16;
  for (int k0 = 0; k0 < NFEAT; k0 += 32) {
    {
      const float* hs = H + (size_t)(row0 + sr) * NFEAT + k0 + sh;
      float av[16];
      *reinterpret_cast<float4*>(&av[0])  = *reinterpret_cast<const float4*>(hs);
      *reinterpret_cast<float4*>(&av[4])  = *reinterpret_cast<const float4*>(hs + 4);
      *reinterpret_cast<float4*>(&av[8])  = *reinterpret_cast<const float4*>(hs + 8);
      *reinterpret_cast<float4*>(&av[12]) = *reinterpret_cast<const float4*>(hs + 12);
      uint uh[8], ul[8];
#pragma unroll
      for (int q = 0; q < 8; ++q) {
        ushort h0 = f2b(av[2 * q]), h1 = f2b(av[2 * q + 1]);
        ushort l0 = f2b(av[2 * q] - b2f(h0)), l1 = f2b(av[2 * q + 1] - b2f(h1));
        uh[q] = (uint)h0 | ((uint)h1 << 16);
        ul[q] = (uint)l0 | ((uint)l1 << 16);
      }
      *reinterpret_cast<uint4*>(&Ah[sr * 40 + sh])     = make_uint4(uh[0], uh[1], uh[2], uh[3]);
      *reinterpret_cast<uint4*>(&Ah[sr * 40 + sh + 8]) = make_uint4(uh[4], uh[5], uh[6], uh[7]);
      *reinterpret_cast<uint4*>(&Al[sr * 40 + sh])     = make_uint4(ul[0], ul[1], ul[2], ul[3]);
      *reinterpret_cast<uint4*>(&Al[sr * 40 + sh + 8]) = make_uint4(ul[4], ul[5], ul[6], ul[7]);
      if (tid < 96) {
        int n = tid >> 1, h2 = (tid & 1) * 16;
        size_t boff = (size_t)n * NFEAT + k0 + h2;
        *reinterpret_cast<uint4*>(&Bh[n * 40 + h2])     = *reinterpret_cast<const uint4*>(bt2h + boff);
        *reinterpret_cast<uint4*>(&Bh[n * 40 + h2 + 8]) = *reinterpret_cast<const uint4*>(bt2h + boff + 8);
        *reinterpret_cast<uint4*>(&Bl[n * 40 + h2])     = *reinterpret_cast<const uint4*>(bt2l + boff);
        *reinterpret_cast<uint4*>(&Bl[n * 40 + h2 + 8]) = *reinterpret_cast<const uint4*>(bt2l + boff + 8);
      }
    }
    __syncthreads();
    bf16x8 afh[2], afl[2], bfh[3], bfl[3];
#pragma unroll
    for (int rt = 0; rt < 2; ++rt) {
      afh[rt] = *reinterpret_cast<const bf16x8*>(&Ah[(w * 32 + rt * 16 + fr) * 40 + quad * 8]);
      afl[rt] = *reinterpret_cast<const bf16x8*>(&Al[(w * 32 + rt * 16 + fr) * 40 + quad * 8]);
    }
#pragma unroll
    for (int ct = 0; ct < 3; ++ct) {
      bfh[ct] = *reinterpret_cast<const bf16x8*>(&Bh[(ct * 16 + fr) * 40 + quad * 8]);
      bfl[ct] = *reinterpret_cast<const bf16x8*>(&Bl[(ct * 16 + fr) * 40 + quad * 8]);
    }
#pragma unroll
    for (int rt = 0; rt < 2; ++rt)
#pragma unroll
      for (int ct = 0; ct < 3; ++ct) {
        acc[rt][ct] = __builtin_amdgcn_mfma_f32_16x16x32_bf16(afl[rt], bfh[ct], acc[rt][ct], 0, 0, 0);
        acc[rt][ct] = __builtin_amdgcn_mfma_f32_16x16x32_bf16(afh[rt], bfl[ct], acc[rt][ct], 0, 0, 0);
        acc[rt][ct] = __builtin_amdgcn_mfma_f32_16x16x32_bf16(afh[rt], bfh[ct], acc[rt][ct], 0, 0, 0);
      }
    __syncthreads();
  }
  // store Wh2 + f1b/f2b + colsums + minmax
  float a1v[3], a2v[3];
#pragma unroll
  for (int ct = 0; ct < 3; ++ct) {
    int col = ct * 16 + fr;
    a1v[ct] = (col < NCLASS) ? a_out[col] : 0.f;
    a2v[ct] = (col < NCLASS) ? a_out[NCLASS + col] : 0.f;
  }
#pragma unroll
  for (int rt = 0; rt < 2; ++rt)
#pragma unroll
    for (int i = 0; i < 4; ++i) {
      int row = row0 + w * 32 + rt * 16 + quad * 4 + i;
      float s1 = 0.f, s2 = 0.f;
#pragma unroll
      for (int ct = 0; ct < 3; ++ct) {
        int col = ct * 16 + fr;
        float v = acc[rt][ct][i];
        if (col < NCLASS) Wh2[(size_t)row * NCLASS + col] = v;
        s1 += v * a1v[ct];
        s2 += v * a2v[ct];
      }
#pragma unroll
      for (int m = 1; m < 16; m <<= 1) { s1 += __shfl_xor(s1, m, 64); s2 += __shfl_xor(s2, m, 64); }
      if (fr == 0) {
        f1bv[row] = s1;
        f2bv[row] = s2;
        atomicMax(&lmax, encf(s2));
        atomicMax(&lmin, ~encf(s2));
      }
    }
#pragma unroll
  for (int ct = 0; ct < 3; ++ct) {
    float v = 0.f;
#pragma unroll
    for (int rt = 0; rt < 2; ++rt)
#pragma unroll
      for (int i = 0; i < 4; ++i) v += acc[rt][ct][i];
    v += __shfl_xor(v, 16, 64);
    v += __shfl_xor(v, 32, 64);
    if (quad == 0) atomicAdd(&cs[ct * 16 + fr], v);
  }
  __syncthreads();
  if (tid < NCLASS) atomicAdd(&meanS2[tid], cs[tid]);
  if (tid == 0) { atomicMax(&mm2[0], lmax); atomicMax(&mm2[1], lmin); }
}

// ---------------- bucket: hist + prefix + scatter in one kernel, one block per head ----------
__global__ __launch_bounds__(1024) void bucket_k(const float* __restrict__ f2,
                                                 const uint* __restrict__ mm,
                                                 int* __restrict__ bs,
                                                 int* __restrict__ idxs,
                                                 float* __restrict__ f2s,
                                                 float* __restrict__ g) {
  __shared__ int sb[NB];
  const int head = blockIdx.x, tid = threadIdx.x;
  const int base = head * N_NODES;
  float3 rg = load_rng(mm, head);
#pragma unroll
  for (int r = 0; r < NB / 1024; ++r) sb[tid + r * 1024] = 0;
  __syncthreads();
  float v[8];
  int bk[8];
#pragma unroll
  for (int r = 0; r < 8; ++r) {
    v[r] = f2[base + tid + r * 1024];
    bk[r] = bucket_of(v[r], rg.x, rg.y);
    atomicAdd(&sb[bk[r]], 1);
  }
  __syncthreads();
  for (int st = 1; st < NB; st <<= 1) {
    int t[NB / 1024];
#pragma unroll
    for (int r = 0; r < NB / 1024; ++r) { int i = tid + r * 1024; t[r] = (i >= st) ? sb[i - st] : 0; }
    __syncthreads();
#pragma unroll
    for (int r = 0; r < NB / 1024; ++r) sb[tid + r * 1024] += t[r];
    __syncthreads();
  }
  int ex[NB / 1024];
#pragma unroll
  for (int r = 0; r < NB / 1024; ++r) {
    int b = tid + r * 1024;
    ex[r] = b ? sb[b - 1] : 0;
    bs[head * (NB + 1) + b] = ex[r];
  }
  if (tid == 0) bs[head * (NB + 1) + NB] = sb[NB - 1];
  __syncthreads();
#pragma unroll
  for (int r = 0; r < NB / 1024; ++r) sb[tid + r * 1024] = ex[r];
  __syncthreads();
#pragma unroll
  for (int r = 0; r < 8; ++r) {
    int pos = atomicAdd(&sb[bk[r]], 1);
    int i = tid + r * 1024;
    idxs[base + pos] = i;
    f2s[base + pos] = v[r];
    g[base + pos] = expf(v[r] - rg.z);
  }
}

// ---------------- suffix scan phase A ----------------
template <int F, int LD, int COLSTEP>
__global__ __launch_bounds__(256) void scanA_k(const float* __restrict__ Wh,
                                               const float* __restrict__ g,
                                               const int* __restrict__ idxs,
                                               float* __restrict__ S,
                                               float* __restrict__ D,
                                               float* __restrict__ T_,
                                               float* __restrict__ Td) {
  constexpr int PAD = (F == 64) ? 66 : 42;
  const int head = blockIdx.y, chunk = blockIdx.x;
  const int tid = threadIdx.x, w = tid >> 6, lane = tid & 63;
  const int base = head << 13;
  const int kbase = base + chunk * CHUNK;
  __shared__ float Sloc[64][PAD];
  __shared__ float Dloc[64];
  __shared__ float wtot[4][PAD];
  __shared__ float wtotD[4];
  int myj = 0; float myg = 0.f;
  if (lane < 16) {
    myj = idxs[kbase + w * 16 + lane];
    myg = g[kbase + w * 16 + lane];
  }
  float acc = 0.f, accD = 0.f;
#pragma unroll
  for (int kk = 15; kk >= 0; --kk) {
    int j = __shfl(myj, kk, 64);
    float gk = __shfl(myg, kk, 64);
    float wv = (lane < F) ? Wh[(size_t)j * LD + head * COLSTEP + lane] : 0.f;
    acc += gk * wv;
    accD += gk;
    if (lane < F) Sloc[w * 16 + kk][lane] = acc;
    if (lane == 0) Dloc[w * 16 + kk] = accD;
  }
  if (lane < F) wtot[w][lane] = acc;
  if (lane == 0) wtotD[w] = accD;
  __syncthreads();
  float off = 0.f, offD = 0.f;
#pragma unroll
  for (int w2 = 1; w2 < 4; ++w2) {
    if (w + w2 < 4) {
      off += (lane < F) ? wtot[w + w2][lane] : 0.f;
      offD += wtotD[w + w2];
    }
  }
#pragma unroll
  for (int kk = 0; kk < 16; ++kk) {
    int e = w * 16 + kk;
    if (lane < F) S[(size_t)(kbase + e) * F + lane] = Sloc[e][lane] + off;
    if (lane == 0) D[kbase + e] = Dloc[e] + offD;
  }
  if (w == 0) {
    if (lane < F) T_[(size_t)(head * NCHUNK + chunk) * F + lane] = wtot[0][lane] + off;
    if (lane == 0) Td[head * NCHUNK + chunk] = wtotD[0] + offD;
  }
}

// ---------------- suffix scan phase B ----------------
template <int F>
__global__ __launch_bounds__(1024) void scanB_k(float* __restrict__ T_, float* __restrict__ Td) {
  __shared__ float s[NCHUNK * F];
  __shared__ float td[NCHUNK];
  int head = blockIdx.x;
  int tid = threadIdx.x, slot = tid >> 6, lane = tid & 63;
#pragma unroll
  for (int r = 0; r < 8; ++r) {
    int c = r * 16 + slot;
    if (lane < F) s[c * F + lane] = T_[(size_t)(head * NCHUNK + c) * F + lane];
  }
  if (tid < NCHUNK) td[tid] = Td[head * NCHUNK + tid];
  __syncthreads();
  for (int st = 1; st < NCHUNK; st <<= 1) {
    float v[8];
    float tv = 0.f;
#pragma unroll
    for (int r = 0; r < 8; ++r) {
      int c = r * 16 + slot;
      v[r] = (lane < F && c + st < NCHUNK) ? s[(c + st) * F + lane] : 0.f;
    }
    if (tid < NCHUNK && tid + st < NCHUNK) tv = td[tid + st];
    __syncthreads();
#pragma unroll
    for (int r = 0; r < 8; ++r) {
      int c = r * 16 + slot;
      if (lane < F) s[c * F + lane] += v[r];
    }
    if (tid < NCHUNK) td[tid] += tv;
    __syncthreads();
  }
#pragma unroll
  for (int r = 0; r < 8; ++r) {
    int c = r * 16 + slot;
    if (lane < F) T_[(size_t)(head * NCHUNK + c) * F + lane] = s[c * F + lane];
  }
  if (tid < NCHUNK) Td[head * NCHUNK + tid] = td[tid];
}

// ---------------- layer-1 queries ----------------
__global__ __launch_bounds__(256) void query1_k(const float* __restrict__ f1,
                                                const float* __restrict__ f2s,
                                                const int* __restrict__ idxs,
                                                const float* __restrict__ Wh,
                                                const float* __restrict__ S,
                                                const float* __restrict__ D,
                                                const float* __restrict__ T_,
                                                const float* __restrict__ Td,
                                                const uint* __restrict__ mm,
                                                const int* __restrict__ bs,
                                                const float* __restrict__ meanS,
                                                float* __restrict__ H) {
  int w = blockIdx.x * 4 + (threadIdx.x >> 6);
  int lane = threadIdx.x & 63;
  int head = w & 7, i = w >> 3, base = head << 13;
  float t = f1[base + i];
  float3 rg = load_rng(mm, head);
  int B0 = bucket_of(-t, rg.x, rg.y);
  int p0 = bs[head * (NB + 1) + B0], p1 = bs[head * (NB + 1) + B0 + 1];
  float num = 0.f, den = 0.f;
  int cnt = N_NODES - p1;
  if (p1 < N_NODES) {
    int c = p1 >> 6;
    num = S[(size_t)(base + p1) * NHID + lane] +
          ((c + 1 < NCHUNK) ? T_[(size_t)(head * NCHUNK + c + 1) * NHID + lane] : 0.f);
    den = D[base + p1] + ((c + 1 < NCHUNK) ? Td[head * NCHUNK + c + 1] : 0.f);
  }
  for (int p = p0; p < p1; ++p) {
    float v = f2s[base + p];
    if (t + v > 0.f) {
      int j = idxs[base + p];
      float gk = expf(v - rg.z);
      num += gk * Wh[(size_t)j * NFEAT + head * NHID + lane];
      den += gk;
      ++cnt;
    }
  }
  float val = cnt ? num / den : meanS[head * NHID + lane] * (1.f / N_NODES);
  H[(size_t)i * NFEAT + head * NHID + lane] = (val > 0.f) ? val : expm1f(val);
}

// ---------------- layer-2 queries + elu + log_softmax ----------------
__global__ __launch_bounds__(256) void final_k(const float* __restrict__ f1b,
                                               const float* __restrict__ f2bs,
                                               const int* __restrict__ idx2,
                                               const float* __restrict__ Wh2,
                                               const float* __restrict__ S2,
                                               const float* __restrict__ D2,
                                               const float* __restrict__ T2,
                                               const float* __restrict__ Td2,
                                               const uint* __restrict__ mm2,
                                               const int* __restrict__ bs2,
                                               const float* __restrict__ meanS2,
                                               float* __restrict__ out) {
  int i = blockIdx.x * 4 + (threadIdx.x >> 6);
  int lane = threadIdx.x & 63;
  float t = f1b[i];
  float3 rg = load_rng(mm2, 0);
  int B0 = bucket_of(-t, rg.x, rg.y);
  int p0 = bs2[B0], p1 = bs2[B0 + 1];
  float num = 0.f, den = 0.f;
  int cnt = N_NODES - p1;
  if (p1 < N_NODES) {
    int c = p1 >> 6;
    num = (lane < NCLASS) ? (S2[(size_t)p1 * NCLASS + lane] +
                             ((c + 1 < NCHUNK) ? T2[(size_t)(c + 1) * NCLASS + lane] : 0.f))
                          : 0.f;
    den = D2[p1] + ((c + 1 < NCHUNK) ? Td2[c + 1] : 0.f);
  }
  for (int p = p0; p < p1; ++p) {
    float v = f2bs[p];
    if (t + v > 0.f) {
      int j = idx2[p];
      float gk = expf(v - rg.z);
      if (lane < NCLASS) num += gk * Wh2[(size_t)j * NCLASS + lane];
      den += gk;
      ++cnt;
    }
  }
  float o;
  if (lane < NCLASS) {
    float val = cnt ? num / den : meanS2[lane] * (1.f / N_NODES);
    o = (val > 0.f) ? val : expm1f(val);
  } else {
    o = -INFINITY;
  }
  float m = o;
#pragma unroll
  for (int msk = 32; msk; msk >>= 1) m = fmaxf(m, __shfl_xor(m, msk, 64));
  float e = (lane < NCLASS) ? expf(o - m) : 0.f;
#pragma unroll
  for (int msk = 32; msk; msk >>= 1) e += __shfl_xor(e, msk, 64);
  if (lane < NCLASS) out[(size_t)i * NCLASS + lane] = o - m - logf(e);
}

extern "C" void kernel_launch(void* const* d_in, const int* in_sizes, int n_in,
                              void* d_out, int out_size, void* d_ws, size_t ws_size,
                              hipStream_t stream) {
  const float* x       = (const float*)d_in[0];
  const float* W_heads = (const float*)d_in[2];
  const float* a_heads = (const float*)d_in[3];
  const float* W_out   = (const float*)d_in[4];
  const float* a_out   = (const float*)d_in[5];
  float* out = (float*)d_out;

  float* ws = (float*)d_ws;
  size_t o = 0;
  auto alloc = [&](size_t n) { float* p = ws + o; o += (n + 3) & ~(size_t)3; return p; };
  float*  S1     = alloc((size_t)NHEADS * N_NODES * NHID);   // 16 MB
  ushort* BTh    = (ushort*)alloc((size_t)NFEAT * NFEAT / 2);
  ushort* BTl    = (ushort*)alloc((size_t)NFEAT * NFEAT / 2);
  ushort* BT2h   = (ushort*)alloc((size_t)48 * NFEAT / 2);
  ushort* BT2l   = (ushort*)alloc((size_t)48 * NFEAT / 2);
  float*  Wh     = alloc((size_t)N_NODES * NFEAT);           // 16 MB fp32
  float*  H      = alloc((size_t)N_NODES * NFEAT);           // 16 MB
  float*  f1     = alloc(NHEADS * N_NODES);
  float*  f2     = alloc(NHEADS * N_NODES);
  float*  f2s    = alloc(NHEADS * N_NODES);
  int*    idxs   = (int*)alloc(NHEADS * N_NODES);
  float*  g1     = alloc(NHEADS * N_NODES);
  float*  D1     = alloc(NHEADS * N_NODES);
  float*  T1     = alloc(NHEADS * NCHUNK * NHID);
  float*  Td1    = alloc(NHEADS * NCHUNK);
  int*    bst1   = (int*)alloc(NHEADS * (NB + 1));
  float*  Wh2    = alloc((size_t)N_NODES * NCLASS);
  float*  S2     = alloc((size_t)N_NODES * NCLASS);
  float*  f1b    = alloc(N_NODES);
  float*  f2b    = alloc(N_NODES);
  float*  f2bs   = alloc(N_NODES);
  int*    idx2   = (int*)alloc(N_NODES);
  float*  g2     = alloc(N_NODES);
  float*  D2     = alloc(N_NODES);
  float*  T2     = alloc(NCHUNK * NCLASS);
  float*  Td2    = alloc(NCHUNK);
  int*    bst2   = (int*)alloc(NB + 1);
  // ---- contiguous zero region (zeroed by prep_k) ----
  float*  zbase  = ws + o;
  uint*   mm1    = (uint*)alloc(16);
  uint*   mm2    = (uint*)alloc(4);
  float*  meanS1 = alloc(NHEADS * NHID);
  float*  meanS2 = alloc(64);
  int zcount = (int)((ws + o) - zbase);

  // ---- layer 1 ----
  prep_k<<<1024 + 96, 256, 0, stream>>>(W_heads, W_out, BTh, BTl, BT2h, BT2l, zbase, zcount);
  gemm1_k<<<dim3(4, 64), 256, 0, stream>>>(x, BTh, BTl, a_heads, Wh, f1, f2, meanS1, mm1);
  bucket_k<<<NHEADS, 1024, 0, stream>>>(f2, mm1, bst1, idxs, f2s, g1);
  scanA_k<NHID, NFEAT, NHID><<<dim3(NCHUNK, NHEADS), 256, 0, stream>>>(Wh, g1, idxs, S1, D1, T1, Td1);
  scanB_k<NHID><<<NHEADS, 1024, 0, stream>>>(T1, Td1);
  query1_k<<<16384, 256, 0, stream>>>(f1, f2s, idxs, Wh, S1, D1, T1, Td1, mm1, bst1, meanS1, H);

  // ---- layer 2 ----
  gemm2_k<<<64, 256, 0, stream>>>(H, BT2h, BT2l, a_out, Wh2, f1b, f2b, meanS2, mm2);
  bucket_k<<<1, 1024, 0, stream>>>(f2b, mm2, bst2, idx2, f2bs, g2);
  scanA_k<NCLASS, NCLASS, 0><<<dim3(NCHUNK, 1), 256, 0, stream>>>(Wh2, g2, idx2, S2, D2, T2, Td2);
  scanB_k<NCLASS><<<1, 1024, 0, stream>>>(T2, Td2);
  final_k<<<2048, 256, 0, stream>>>(f1b, f2bs, idx2, Wh2, S2, D2, T2, Td2, mm2, bst2, meanS2, out);
}